// Round 1
// baseline (2943.109 us; speedup 1.0000x reference)
//
#include <hip/hip_runtime.h>

#define N_NODES 100000
#define N_EDGES 3200000

// ---------- CSR build ----------

// edge_index may be int64 (reference decl) or int32 (if x64 disabled in harness).
// Values < 100000 < 2^17, so if int64, dwords 1,3,5,7 are all zero; if int32,
// the probability of four consecutive src values being 0 is ~1e-20.
__global__ void detect_fmt(const unsigned int* __restrict__ e, int* __restrict__ flag) {
    if (blockIdx.x == 0 && threadIdx.x == 0)
        *flag = (e[1] == 0u && e[3] == 0u && e[5] == 0u && e[7] == 0u) ? 1 : 0;
}

__global__ void convert_edges(const void* __restrict__ edges, const int* __restrict__ flag,
                              int* __restrict__ conv, int n) {
    int i = blockIdx.x * blockDim.x + threadIdx.x;
    if (i >= n) return;
    if (*flag) conv[i] = (int)((const long long*)edges)[i];
    else       conv[i] = ((const int*)edges)[i];
}

__global__ void hist_kernel(const int* __restrict__ dst, int* __restrict__ count, int E) {
    int i = blockIdx.x * blockDim.x + threadIdx.x;
    if (i < E) atomicAdd(&count[dst[i]], 1);
}

// Single-block exclusive scan over N counts -> row_ptr[N+1], plus cursor copy.
__global__ void scan_kernel(const int* __restrict__ count, int* __restrict__ row_ptr,
                            int* __restrict__ cursor, int n) {
    __shared__ int sums[1024];
    int t = threadIdx.x;
    int chunk = (n + 1023) >> 10;
    int beg = t * chunk;
    int end = min(beg + chunk, n);
    int s = 0;
    for (int i = beg; i < end; ++i) s += count[i];
    sums[t] = s;
    __syncthreads();
    int val = s;
    for (int off = 1; off < 1024; off <<= 1) {
        int other = (t >= off) ? sums[t - off] : 0;
        __syncthreads();
        val += other;
        sums[t] = val;
        __syncthreads();
    }
    int run = val - s;  // exclusive prefix of this chunk
    for (int i = beg; i < end; ++i) {
        row_ptr[i] = run;
        cursor[i] = run;
        run += count[i];
    }
    if (end >= n) row_ptr[n] = run;  // all qualifying threads write the same total
}

__global__ void scatter_kernel(const int* __restrict__ src, const int* __restrict__ dst,
                               int* __restrict__ cursor, int* __restrict__ esorted, int E) {
    int i = blockIdx.x * blockDim.x + threadIdx.x;
    if (i < E) {
        int p = atomicAdd(&cursor[dst[i]], 1);
        esorted[p] = src[i];
    }
}

// ---------- per-layer kernels ----------

// One wave per node: x[v] = h[v] + sum_{u in in(v)} h[u].  Lane l owns float2
// at dims (2l, 2l+1) -> one 512B row per dwordx2 wave load.
__global__ __launch_bounds__(256) void agg_kernel(const float* __restrict__ h,
                                                  const int* __restrict__ row_ptr,
                                                  const int* __restrict__ esrc,
                                                  float* __restrict__ x) {
    int lane = threadIdx.x & 63;
    int wid = (blockIdx.x * blockDim.x + threadIdx.x) >> 6;
    int nw = (gridDim.x * blockDim.x) >> 6;
    for (int v = wid; v < N_NODES; v += nw) {
        float2 a = ((const float2*)&h[v * 128])[lane];
        int beg = row_ptr[v], end = row_ptr[v + 1];
        int i = beg;
        // 4-way unroll: 4 gather loads in flight per wave
        for (; i + 4 <= end; i += 4) {
            int u0 = esrc[i], u1 = esrc[i + 1], u2 = esrc[i + 2], u3 = esrc[i + 3];
            float2 h0 = ((const float2*)&h[u0 * 128])[lane];
            float2 h1 = ((const float2*)&h[u1 * 128])[lane];
            float2 h2 = ((const float2*)&h[u2 * 128])[lane];
            float2 h3 = ((const float2*)&h[u3 * 128])[lane];
            a.x += (h0.x + h1.x) + (h2.x + h3.x);
            a.y += (h0.y + h1.y) + (h2.y + h3.y);
        }
        for (; i < end; ++i) {
            int u = esrc[i];
            float2 hu = ((const float2*)&h[u * 128])[lane];
            a.x += hu.x;
            a.y += hu.y;
        }
        ((float2*)&x[v * 128])[lane] = a;
    }
}

// y = x @ W + b.  W (128 x DOUT) staged in LDS (64KB max for DOUT=128 -> x row
// broadcast via __shfl, not LDS).  One wave per node; lane l holds x[2l],x[2l+1].
template <int DOUT>
__global__ __launch_bounds__(256) void mlp_kernel(const float* __restrict__ x,
                                                  const float* __restrict__ W,
                                                  const float* __restrict__ b,
                                                  float* __restrict__ y) {
    __shared__ float Ws[128 * DOUT];
    for (int i = threadIdx.x; i < 128 * DOUT; i += blockDim.x) Ws[i] = W[i];
    __syncthreads();
    int lane = threadIdx.x & 63;
    int wid = (blockIdx.x * blockDim.x + threadIdx.x) >> 6;
    int nw = (gridDim.x * blockDim.x) >> 6;
    float bias0 = b[lane];
    float bias1 = (DOUT == 128) ? b[64 + lane] : 0.0f;
    for (int v = wid; v < N_NODES; v += nw) {
        float2 a = ((const float2*)&x[v * 128])[lane];
        float acc0 = bias0, acc1 = bias1;
#pragma unroll 16
        for (int k0 = 0; k0 < 64; ++k0) {
            float px = __shfl(a.x, k0);
            float py = __shfl(a.y, k0);
            acc0 += px * Ws[(2 * k0) * DOUT + lane];
            acc0 += py * Ws[(2 * k0 + 1) * DOUT + lane];
            if (DOUT == 128) {
                acc1 += px * Ws[(2 * k0) * DOUT + 64 + lane];
                acc1 += py * Ws[(2 * k0 + 1) * DOUT + 64 + lane];
            }
        }
        y[v * DOUT + lane] = acc0;
        if (DOUT == 128) y[v * DOUT + 64 + lane] = acc1;
    }
}

extern "C" void kernel_launch(void* const* d_in, const int* in_sizes, int n_in,
                              void* d_out, int out_size, void* d_ws, size_t ws_size,
                              hipStream_t stream) {
    const float* h_in = (const float*)d_in[0];
    const void* edges = d_in[1];
    const float* W[5] = {(const float*)d_in[2], (const float*)d_in[4], (const float*)d_in[6],
                         (const float*)d_in[8], (const float*)d_in[10]};
    const float* B[5] = {(const float*)d_in[3], (const float*)d_in[5], (const float*)d_in[7],
                         (const float*)d_in[9], (const float*)d_in[11]};

    // workspace layout
    size_t off = 0;
    auto alloc = [&](size_t bytes) {
        void* p = (char*)d_ws + off;
        off = (off + bytes + 255) & ~(size_t)255;
        return p;
    };
    int* esorted = (int*)alloc((size_t)N_EDGES * 4);       // 12.8 MB
    int* row_ptr = (int*)alloc((size_t)(N_NODES + 1) * 4);
    int* cursor = (int*)alloc((size_t)N_NODES * 4);
    int* count = (int*)alloc((size_t)N_NODES * 4);
    int* flag = (int*)alloc(256);
    float* C = (float*)alloc((size_t)N_NODES * 128 * 4);   // 51.2 MB (x = h+agg)
    float* D = (float*)alloc((size_t)N_NODES * 128 * 4);   // 51.2 MB (layer output ping)
    int* conv = (int*)D;  // alias: conv (25.6MB) only live during CSR build, before D is used

    // ---- build CSR (counting sort by dst) ----
    detect_fmt<<<1, 64, 0, stream>>>((const unsigned int*)edges, flag);
    int n2e = 2 * N_EDGES;
    convert_edges<<<(n2e + 255) / 256, 256, 0, stream>>>(edges, flag, conv, n2e);
    hipMemsetAsync(count, 0, (size_t)N_NODES * 4, stream);
    hist_kernel<<<(N_EDGES + 255) / 256, 256, 0, stream>>>(conv + N_EDGES, count, N_EDGES);
    scan_kernel<<<1, 1024, 0, stream>>>(count, row_ptr, cursor, N_NODES);
    scatter_kernel<<<(N_EDGES + 255) / 256, 256, 0, stream>>>(conv, conv + N_EDGES, cursor,
                                                              esorted, N_EDGES);

    // ---- 5 GIN layers ----
    const int AGG_BLOCKS = 2048;  // 8192 waves, grid-stride over 100K nodes
    const int MLP_BLOCKS = 1024;

    // L0: h_in -> C -> D
    agg_kernel<<<AGG_BLOCKS, 256, 0, stream>>>(h_in, row_ptr, esorted, C);
    mlp_kernel<128><<<MLP_BLOCKS, 256, 0, stream>>>(C, W[0], B[0], D);
    // L1..L3: D -> C -> D
    for (int l = 1; l <= 3; ++l) {
        agg_kernel<<<AGG_BLOCKS, 256, 0, stream>>>(D, row_ptr, esorted, C);
        mlp_kernel<128><<<MLP_BLOCKS, 256, 0, stream>>>(C, W[l], B[l], D);
    }
    // L4: D -> C -> d_out (64-dim)
    agg_kernel<<<AGG_BLOCKS, 256, 0, stream>>>(D, row_ptr, esorted, C);
    mlp_kernel<64><<<MLP_BLOCKS, 256, 0, stream>>>(C, W[4], B[4], (float*)d_out);
}

// Round 2
// 2193.069 us; speedup vs baseline: 1.3420x; 1.3420x over previous
//
#include <hip/hip_runtime.h>

#define N_NODES 100000
#define N_EDGES 3200000
#define NB 782      // dst buckets of 128 nodes each: ceil(100000/128)
#define BCAP 5120   // max edges per bucket (avg 4096, 16σ guard)

// ---------- CSR build ----------

// edge_index may be int64 (reference decl) or int32. Values < 2^17, so if
// int64 the odd dwords are zero; prob of 4 consecutive int32 srcs == 0 ~ 0.
__global__ void detect_fmt(const unsigned int* __restrict__ e, int* __restrict__ flag,
                           int* __restrict__ row_ptr) {
    if (threadIdx.x == 0) {
        *flag = (e[1] == 0u && e[3] == 0u && e[5] == 0u && e[7] == 0u) ? 1 : 0;
        row_ptr[N_NODES] = N_EDGES;
    }
}

__device__ __forceinline__ int load_idx(const void* edges, int fmt, long long i) {
    return fmt ? (int)((const long long*)edges)[i] : ((const int*)edges)[i];
}

// Pass A1: per-bucket histogram (LDS-staged to keep global atomics cheap).
__global__ __launch_bounds__(256) void bucket_hist(const void* __restrict__ edges,
                                                   const int* __restrict__ flag,
                                                   int* __restrict__ bcount) {
    __shared__ int cnt[NB];
    for (int i = threadIdx.x; i < NB; i += blockDim.x) cnt[i] = 0;
    __syncthreads();
    int fmt = *flag;
    int stride = gridDim.x * blockDim.x;
    for (int i = blockIdx.x * blockDim.x + threadIdx.x; i < N_EDGES; i += stride) {
        int dst = load_idx(edges, fmt, (long long)N_EDGES + i);
        atomicAdd(&cnt[dst >> 7], 1);
    }
    __syncthreads();
    for (int i = threadIdx.x; i < NB; i += blockDim.x)
        if (cnt[i]) atomicAdd(&bcount[i], cnt[i]);
}

// Generic single-block exclusive scan: count[n] -> off[n+1] (incl. total), cur copy.
__global__ void scan_kernel(const int* __restrict__ count, int* __restrict__ off_out,
                            int* __restrict__ cur, int n) {
    __shared__ int sums[1024];
    int t = threadIdx.x;
    int chunk = (n + 1023) >> 10;
    int beg = t * chunk;
    int end = min(beg + chunk, n);
    int s = 0;
    for (int i = beg; i < end; ++i) s += count[i];
    sums[t] = s;
    __syncthreads();
    int val = s;
    for (int off = 1; off < 1024; off <<= 1) {
        int other = (t >= off) ? sums[t - off] : 0;
        __syncthreads();
        val += other;
        sums[t] = val;
        __syncthreads();
    }
    int run = val - s;  // exclusive prefix of this chunk
    for (int i = beg; i < end; ++i) {
        off_out[i] = run;
        cur[i] = run;
        run += count[i];
    }
    if (end >= n) off_out[n] = run;
}

// Pass A2: scatter edges into bucket-contiguous tmp. Only ~782 append streams
// -> L2 write-combines full lines (vs 100K streams before).
__global__ __launch_bounds__(256) void bucket_scatter(const void* __restrict__ edges,
                                                      const int* __restrict__ flag,
                                                      int* __restrict__ bcur,
                                                      unsigned int* __restrict__ tmp) {
    int i = blockIdx.x * blockDim.x + threadIdx.x;
    if (i >= N_EDGES) return;
    int fmt = *flag;
    int src = load_idx(edges, fmt, i);
    int dst = load_idx(edges, fmt, (long long)N_EDGES + i);
    int b = dst >> 7;
    int pos = atomicAdd(&bcur[b], 1);
    tmp[pos] = ((unsigned)(dst & 127) << 17) | (unsigned)src;  // src < 2^17
}

// Pass B: per-bucket in-LDS counting sort + local row_ptr; esorted written coalesced.
__global__ __launch_bounds__(256) void bucket_finalize(const unsigned int* __restrict__ tmp,
                                                       const int* __restrict__ boff,
                                                       int* __restrict__ row_ptr,
                                                       int* __restrict__ esorted) {
    __shared__ unsigned int s1[BCAP];
    __shared__ int s2[BCAP];
    __shared__ int cnt[128], pref[128], cur[128];
    int b = blockIdx.x;
    int beg = boff[b];
    int n = boff[b + 1] - beg;
    if (n > BCAP) n = BCAP;  // unreachable statistically; memory-safety guard
    int t = threadIdx.x;
    if (t < 128) cnt[t] = 0;
    __syncthreads();
    for (int e = t; e < n; e += 256) {
        unsigned k = tmp[beg + e];
        s1[e] = k;
        atomicAdd(&cnt[k >> 17], 1);
    }
    __syncthreads();
    if (t < 128) pref[t] = cnt[t];
    __syncthreads();
    for (int off = 1; off < 128; off <<= 1) {
        int v = (t < 128 && t >= off) ? pref[t - off] : 0;
        __syncthreads();
        if (t < 128) pref[t] += v;
        __syncthreads();
    }
    if (t < 128) {
        int ex = pref[t] - cnt[t];  // exclusive prefix
        cur[t] = ex;
        int node = b * 128 + t;
        if (node < N_NODES) row_ptr[node] = beg + ex;
    }
    __syncthreads();
    for (int e = t; e < n; e += 256) {
        unsigned k = s1[e];
        int p = atomicAdd(&cur[k >> 17], 1);
        s2[p] = (int)(k & 0x1FFFF);
    }
    __syncthreads();
    for (int e = t; e < n; e += 256) esorted[beg + e] = s2[e];
}

// ---------- per-layer kernels ----------

// One wave per node: x[v] = h[v] + sum_{u in in(v)} h[u].  Lane l owns float2
// at dims (2l, 2l+1) -> one 512B row per dwordx2 wave load. 8 gathers in flight.
__global__ __launch_bounds__(256) void agg_kernel(const float* __restrict__ h,
                                                  const int* __restrict__ row_ptr,
                                                  const int* __restrict__ esrc,
                                                  float* __restrict__ x) {
    int lane = threadIdx.x & 63;
    int wid = (blockIdx.x * blockDim.x + threadIdx.x) >> 6;
    int nw = (gridDim.x * blockDim.x) >> 6;
    for (int v = wid; v < N_NODES; v += nw) {
        float2 a = ((const float2*)&h[v * 128])[lane];
        int beg = row_ptr[v], end = row_ptr[v + 1];
        int i = beg;
        for (; i + 8 <= end; i += 8) {
            float2 hv[8];
#pragma unroll
            for (int j = 0; j < 8; ++j) {
                int u = esrc[i + j];
                hv[j] = ((const float2*)&h[u * 128])[lane];
            }
#pragma unroll
            for (int j = 0; j < 8; ++j) { a.x += hv[j].x; a.y += hv[j].y; }
        }
        for (; i < end; ++i) {
            int u = esrc[i];
            float2 hu = ((const float2*)&h[u * 128])[lane];
            a.x += hu.x;
            a.y += hu.y;
        }
        ((float2*)&x[v * 128])[lane] = a;
    }
}

// y[M x N] = x[M x 128] @ W[128 x N] + b. Register-tiled fp32 GEMM:
// 256 threads, block tile MT x N, thread tile 8x8, K staged in LDS by 16.
template <int N, int MT>
__global__ __launch_bounds__(256) void mlp_gemm(const float* __restrict__ x,
                                                const float* __restrict__ W,
                                                const float* __restrict__ bias,
                                                float* __restrict__ y) {
    __shared__ float As[16][MT];  // k-major (transposed on store)
    __shared__ float Bs[16][N];
    constexpr int TCN = N / 8;  // col groups: 16 (N=128) or 8 (N=64)
    int tid = threadIdx.x;
    int tc = tid % TCN;
    int tr = tid / TCN;
    int m0 = blockIdx.x * MT;
    float acc[8][8];
#pragma unroll
    for (int i = 0; i < 8; ++i)
#pragma unroll
        for (int j = 0; j < 8; ++j) acc[i][j] = 0.0f;

    for (int k0 = 0; k0 < 128; k0 += 16) {
        // A: MT rows x 16 k. Coalesced: lane loads float4; 4 lanes cover one row's
        // 64B k-slice (exactly one cache line per row per K-step).
#pragma unroll
        for (int i = 0; i < MT / 64; ++i) {  // MT*16/4 float4s / 256 threads
            int idx = tid + i * 256;
            int c4 = idx & 3;
            int r = idx >> 2;
            int m = m0 + r;
            if (m >= N_NODES) m = N_NODES - 1;
            float4 v = *(const float4*)&x[(size_t)m * 128 + k0 + c4 * 4];
            As[c4 * 4 + 0][r] = v.x;
            As[c4 * 4 + 1][r] = v.y;
            As[c4 * 4 + 2][r] = v.z;
            As[c4 * 4 + 3][r] = v.w;
        }
        // B: 16 k x N, direct copy, coalesced.
#pragma unroll
        for (int i = 0; i < N / 64; ++i) {
            int idx = tid + i * 256;
            int c4 = idx % (N / 4);
            int kr = idx / (N / 4);
            *(float4*)&Bs[kr][c4 * 4] = *(const float4*)&W[(size_t)(k0 + kr) * N + c4 * 4];
        }
        __syncthreads();
#pragma unroll
        for (int k = 0; k < 16; ++k) {
            float4 a0 = *(const float4*)&As[k][tr * 8];
            float4 a1 = *(const float4*)&As[k][tr * 8 + 4];
            float4 b0 = *(const float4*)&Bs[k][tc * 8];
            float4 b1 = *(const float4*)&Bs[k][tc * 8 + 4];
            float av[8] = {a0.x, a0.y, a0.z, a0.w, a1.x, a1.y, a1.z, a1.w};
            float bv[8] = {b0.x, b0.y, b0.z, b0.w, b1.x, b1.y, b1.z, b1.w};
#pragma unroll
            for (int i = 0; i < 8; ++i)
#pragma unroll
                for (int j = 0; j < 8; ++j) acc[i][j] += av[i] * bv[j];
        }
        __syncthreads();
    }
    float bv[8];
#pragma unroll
    for (int j = 0; j < 8; ++j) bv[j] = bias[tc * 8 + j];
#pragma unroll
    for (int i = 0; i < 8; ++i) {
        int m = m0 + tr * 8 + i;
        if (m < N_NODES) {
            float4 o0 = {acc[i][0] + bv[0], acc[i][1] + bv[1], acc[i][2] + bv[2], acc[i][3] + bv[3]};
            float4 o1 = {acc[i][4] + bv[4], acc[i][5] + bv[5], acc[i][6] + bv[6], acc[i][7] + bv[7]};
            *(float4*)&y[(size_t)m * N + tc * 8] = o0;
            *(float4*)&y[(size_t)m * N + tc * 8 + 4] = o1;
        }
    }
}

extern "C" void kernel_launch(void* const* d_in, const int* in_sizes, int n_in,
                              void* d_out, int out_size, void* d_ws, size_t ws_size,
                              hipStream_t stream) {
    const float* h_in = (const float*)d_in[0];
    const void* edges = d_in[1];
    const float* W[5] = {(const float*)d_in[2], (const float*)d_in[4], (const float*)d_in[6],
                         (const float*)d_in[8], (const float*)d_in[10]};
    const float* B[5] = {(const float*)d_in[3], (const float*)d_in[5], (const float*)d_in[7],
                         (const float*)d_in[9], (const float*)d_in[11]};

    size_t off = 0;
    auto alloc = [&](size_t bytes) {
        void* p = (char*)d_ws + off;
        off = (off + bytes + 255) & ~(size_t)255;
        return p;
    };
    int* esorted = (int*)alloc((size_t)N_EDGES * 4);        // 12.8 MB
    int* row_ptr = (int*)alloc((size_t)(N_NODES + 1) * 4);
    int* bcount = (int*)alloc((size_t)NB * 4);
    int* boff = (int*)alloc((size_t)(NB + 1) * 4);
    int* bcur = (int*)alloc((size_t)NB * 4);
    int* flag = (int*)alloc(256);
    float* C = (float*)alloc((size_t)N_NODES * 128 * 4);    // 51.2 MB
    float* D = (float*)alloc((size_t)N_NODES * 128 * 4);    // 51.2 MB
    unsigned int* tmp = (unsigned int*)D;  // alias: only live during build

    // ---- build CSR (bucketed counting sort by dst) ----
    detect_fmt<<<1, 64, 0, stream>>>((const unsigned int*)edges, flag, row_ptr);
    hipMemsetAsync(bcount, 0, (size_t)NB * 4, stream);
    bucket_hist<<<1024, 256, 0, stream>>>(edges, flag, bcount);
    scan_kernel<<<1, 1024, 0, stream>>>(bcount, boff, bcur, NB);
    bucket_scatter<<<(N_EDGES + 255) / 256, 256, 0, stream>>>(edges, flag, bcur, tmp);
    bucket_finalize<<<NB, 256, 0, stream>>>(tmp, boff, row_ptr, esorted);

    // ---- 5 GIN layers ----
    const int AGG_BLOCKS = 2048;

    agg_kernel<<<AGG_BLOCKS, 256, 0, stream>>>(h_in, row_ptr, esorted, C);
    mlp_gemm<128, 128><<<(N_NODES + 127) / 128, 256, 0, stream>>>(C, W[0], B[0], D);
    for (int l = 1; l <= 3; ++l) {
        agg_kernel<<<AGG_BLOCKS, 256, 0, stream>>>(D, row_ptr, esorted, C);
        mlp_gemm<128, 128><<<(N_NODES + 127) / 128, 256, 0, stream>>>(C, W[l], B[l], D);
    }
    agg_kernel<<<AGG_BLOCKS, 256, 0, stream>>>(D, row_ptr, esorted, C);
    mlp_gemm<64, 256><<<(N_NODES + 255) / 256, 256, 0, stream>>>(C, W[4], B[4], (float*)d_out);
}

// Round 3
// 1373.184 us; speedup vs baseline: 2.1433x; 1.5971x over previous
//
#include <hip/hip_runtime.h>

#define N_NODES 100000
#define N_EDGES 3200000
#define NB 782          // dst buckets of 128 nodes: ceil(100000/128)
#define BCAP 5120       // max edges per bucket (avg 4096, 16 sigma guard)
#define CHUNK_EDGES 16384
#define NCHUNKS ((N_EDGES + CHUNK_EDGES - 1) / CHUNK_EDGES)  // 196

// ---------- CSR build: deterministic two-pass bucket partition ----------

// edge_index may be int64 (reference decl) or int32. Values < 2^17, so if
// int64 the odd dwords are zero; prob of 4 consecutive int32 srcs == 0 ~ 0.
__global__ void detect_fmt(const unsigned int* __restrict__ e, int* __restrict__ flag,
                           int* __restrict__ row_ptr) {
    if (threadIdx.x == 0) {
        *flag = (e[1] == 0u && e[3] == 0u && e[5] == 0u && e[7] == 0u) ? 1 : 0;
        row_ptr[N_NODES] = N_EDGES;
    }
}

__device__ __forceinline__ int load_idx(const void* edges, int fmt, long long i) {
    return fmt ? (int)((const long long*)edges)[i] : ((const int*)edges)[i];
}

// Pass 1: per-chunk histogram over buckets (LDS), chunk-major layout so global
// writes are coalesced. bcount accumulated with low-contention atomics
// (196 adds per address, pipelined in L2).
__global__ __launch_bounds__(256) void part_hist(const void* __restrict__ edges,
                                                 const int* __restrict__ flag,
                                                 int* __restrict__ hist2,
                                                 int* __restrict__ bcount) {
    __shared__ int cnt[NB];
    for (int i = threadIdx.x; i < NB; i += 256) cnt[i] = 0;
    __syncthreads();
    int fmt = *flag;
    int c = blockIdx.x;
    int beg = c * CHUNK_EDGES, end = min(beg + CHUNK_EDGES, N_EDGES);
    for (int i = beg + threadIdx.x; i < end; i += 256) {
        int dst = load_idx(edges, fmt, (long long)N_EDGES + i);
        atomicAdd(&cnt[dst >> 7], 1);
    }
    __syncthreads();
    for (int i = threadIdx.x; i < NB; i += 256) {
        hist2[c * NB + i] = cnt[i];
        if (cnt[i]) atomicAdd(&bcount[i], cnt[i]);
    }
}

// Generic single-block exclusive scan: count[n] -> off[n+1] (incl. total).
__global__ void scan_kernel(const int* __restrict__ count, int* __restrict__ off_out, int n) {
    __shared__ int sums[1024];
    int t = threadIdx.x;
    int chunk = (n + 1023) >> 10;
    int beg = t * chunk;
    int end = min(beg + chunk, n);
    int s = 0;
    for (int i = beg; i < end; ++i) s += count[i];
    sums[t] = s;
    __syncthreads();
    int val = s;
    for (int off = 1; off < 1024; off <<= 1) {
        int other = (t >= off) ? sums[t - off] : 0;
        __syncthreads();
        val += other;
        sums[t] = val;
        __syncthreads();
    }
    int run = val - s;  // exclusive prefix of this chunk
    for (int i = beg; i < end; ++i) {
        off_out[i] = run;
        run += count[i];
    }
    if (end >= n) off_out[n] = run;
}

// Per-bucket scan across chunks: base2[c][b] = boff[b] + sum_{c'<c} hist2[c'][b].
// One block per bucket; NCHUNKS (196) <= 256 threads.
__global__ __launch_bounds__(256) void chunk_scan(const int* __restrict__ hist2,
                                                  const int* __restrict__ boff,
                                                  int* __restrict__ base2) {
    __shared__ int s[256];
    int b = blockIdx.x;
    int t = threadIdx.x;
    int v = (t < NCHUNKS) ? hist2[t * NB + b] : 0;
    s[t] = v;
    __syncthreads();
    int val = v;
    for (int off = 1; off < 256; off <<= 1) {
        int o = (t >= off) ? s[t - off] : 0;
        __syncthreads();
        val += o;
        s[t] = val;
        __syncthreads();
    }
    if (t < NCHUNKS) base2[t * NB + b] = boff[b] + val - v;  // exclusive
}

// Pass 2: place edges. All atomics are LDS (~21 edges/counter/block). Each
// (chunk,bucket) output range is a private contiguous stream -> write-combines.
__global__ __launch_bounds__(256) void part_scatter(const void* __restrict__ edges,
                                                    const int* __restrict__ flag,
                                                    const int* __restrict__ base2,
                                                    unsigned int* __restrict__ tmp) {
    __shared__ int cur[NB];
    int c = blockIdx.x;
    for (int i = threadIdx.x; i < NB; i += 256) cur[i] = base2[c * NB + i];
    __syncthreads();
    int fmt = *flag;
    int beg = c * CHUNK_EDGES, end = min(beg + CHUNK_EDGES, N_EDGES);
    for (int i = beg + threadIdx.x; i < end; i += 256) {
        int src = load_idx(edges, fmt, i);
        int dst = load_idx(edges, fmt, (long long)N_EDGES + i);
        int b = dst >> 7;
        int pos = atomicAdd(&cur[b], 1);
        tmp[pos] = ((unsigned)(dst & 127) << 17) | (unsigned)src;  // src < 2^17
    }
}

// Pass 3: per-bucket in-LDS counting sort by dst-local; esorted written
// coalesced; row_ptr derived locally.
__global__ __launch_bounds__(256) void bucket_finalize(const unsigned int* __restrict__ tmp,
                                                       const int* __restrict__ boff,
                                                       int* __restrict__ row_ptr,
                                                       int* __restrict__ esorted) {
    __shared__ unsigned int s1[BCAP];
    __shared__ int s2[BCAP];
    __shared__ int cnt[128], pref[128], cur[128];
    int b = blockIdx.x;
    int beg = boff[b];
    int n = boff[b + 1] - beg;
    if (n > BCAP) n = BCAP;  // statistically unreachable; memory-safety guard
    int t = threadIdx.x;
    if (t < 128) cnt[t] = 0;
    __syncthreads();
    for (int e = t; e < n; e += 256) {
        unsigned k = tmp[beg + e];
        s1[e] = k;
        atomicAdd(&cnt[k >> 17], 1);
    }
    __syncthreads();
    if (t < 128) pref[t] = cnt[t];
    __syncthreads();
    for (int off = 1; off < 128; off <<= 1) {
        int v = (t < 128 && t >= off) ? pref[t - off] : 0;
        __syncthreads();
        if (t < 128) pref[t] += v;
        __syncthreads();
    }
    if (t < 128) {
        int ex = pref[t] - cnt[t];
        cur[t] = ex;
        int node = b * 128 + t;
        if (node < N_NODES) row_ptr[node] = beg + ex;
    }
    __syncthreads();
    for (int e = t; e < n; e += 256) {
        unsigned k = s1[e];
        int p = atomicAdd(&cur[k >> 17], 1);
        s2[p] = (int)(k & 0x1FFFF);
    }
    __syncthreads();
    for (int e = t; e < n; e += 256) esorted[beg + e] = s2[e];
}

// ---------- per-layer kernels ----------
// Layer rewritten via linearity: out = p + agg(p) + bias, where p = h @ W.
// (agg commutes with right-multiplication; bias added once, after agg.)

// One wave per node, 128-dim rows: lane owns float2 (512B/row wave loads).
__global__ __launch_bounds__(256) void agg128(const float* __restrict__ p,
                                              const int* __restrict__ row_ptr,
                                              const int* __restrict__ esrc,
                                              const float* __restrict__ bias,
                                              float* __restrict__ out) {
    int lane = threadIdx.x & 63;
    int wid = (blockIdx.x * blockDim.x + threadIdx.x) >> 6;
    int nw = (gridDim.x * blockDim.x) >> 6;
    float2 bv = ((const float2*)bias)[lane];
    for (int v = wid; v < N_NODES; v += nw) {
        float2 a = ((const float2*)&p[(size_t)v * 128])[lane];
        a.x += bv.x;
        a.y += bv.y;
        int beg = row_ptr[v], end = row_ptr[v + 1];
        int i = beg;
        for (; i + 8 <= end; i += 8) {
            float2 hv[8];
#pragma unroll
            for (int j = 0; j < 8; ++j) {
                int u = esrc[i + j];
                hv[j] = ((const float2*)&p[(size_t)u * 128])[lane];
            }
#pragma unroll
            for (int j = 0; j < 8; ++j) { a.x += hv[j].x; a.y += hv[j].y; }
        }
        for (; i < end; ++i) {
            int u = esrc[i];
            float2 hu = ((const float2*)&p[(size_t)u * 128])[lane];
            a.x += hu.x;
            a.y += hu.y;
        }
        ((float2*)&out[(size_t)v * 128])[lane] = a;
    }
}

// 64-dim rows: lane owns 1 float (256B/row wave loads).
__global__ __launch_bounds__(256) void agg64(const float* __restrict__ p,
                                             const int* __restrict__ row_ptr,
                                             const int* __restrict__ esrc,
                                             const float* __restrict__ bias,
                                             float* __restrict__ out) {
    int lane = threadIdx.x & 63;
    int wid = (blockIdx.x * blockDim.x + threadIdx.x) >> 6;
    int nw = (gridDim.x * blockDim.x) >> 6;
    float bv = bias[lane];
    for (int v = wid; v < N_NODES; v += nw) {
        float a = p[(size_t)v * 64 + lane] + bv;
        int beg = row_ptr[v], end = row_ptr[v + 1];
        int i = beg;
        for (; i + 8 <= end; i += 8) {
            float hv[8];
#pragma unroll
            for (int j = 0; j < 8; ++j) hv[j] = p[(size_t)esrc[i + j] * 64 + lane];
#pragma unroll
            for (int j = 0; j < 8; ++j) a += hv[j];
        }
        for (; i < end; ++i) a += p[(size_t)esrc[i] * 64 + lane];
        out[(size_t)v * 64 + lane] = a;
    }
}

// y[M x N] = x[M x 128] @ W[128 x N] (no bias). Register-tiled fp32 GEMM:
// 256 threads, block tile MT x N, thread tile 8x8, K staged in LDS by 16.
template <int N, int MT>
__global__ __launch_bounds__(256) void mlp_gemm(const float* __restrict__ x,
                                                const float* __restrict__ W,
                                                float* __restrict__ y) {
    __shared__ float As[16][MT];  // k-major (transposed on store)
    __shared__ float Bs[16][N];
    constexpr int TCN = N / 8;
    int tid = threadIdx.x;
    int tc = tid % TCN;
    int tr = tid / TCN;
    int m0 = blockIdx.x * MT;
    float acc[8][8];
#pragma unroll
    for (int i = 0; i < 8; ++i)
#pragma unroll
        for (int j = 0; j < 8; ++j) acc[i][j] = 0.0f;

    for (int k0 = 0; k0 < 128; k0 += 16) {
#pragma unroll
        for (int i = 0; i < MT / 64; ++i) {
            int idx = tid + i * 256;
            int c4 = idx & 3;
            int r = idx >> 2;
            int m = m0 + r;
            if (m >= N_NODES) m = N_NODES - 1;
            float4 v = *(const float4*)&x[(size_t)m * 128 + k0 + c4 * 4];
            As[c4 * 4 + 0][r] = v.x;
            As[c4 * 4 + 1][r] = v.y;
            As[c4 * 4 + 2][r] = v.z;
            As[c4 * 4 + 3][r] = v.w;
        }
#pragma unroll
        for (int i = 0; i < N / 64; ++i) {
            int idx = tid + i * 256;
            int c4 = idx % (N / 4);
            int kr = idx / (N / 4);
            *(float4*)&Bs[kr][c4 * 4] = *(const float4*)&W[(size_t)(k0 + kr) * N + c4 * 4];
        }
        __syncthreads();
#pragma unroll
        for (int k = 0; k < 16; ++k) {
            float4 a0 = *(const float4*)&As[k][tr * 8];
            float4 a1 = *(const float4*)&As[k][tr * 8 + 4];
            float4 b0 = *(const float4*)&Bs[k][tc * 8];
            float4 b1 = *(const float4*)&Bs[k][tc * 8 + 4];
            float av[8] = {a0.x, a0.y, a0.z, a0.w, a1.x, a1.y, a1.z, a1.w};
            float bv[8] = {b0.x, b0.y, b0.z, b0.w, b1.x, b1.y, b1.z, b1.w};
#pragma unroll
            for (int i = 0; i < 8; ++i)
#pragma unroll
                for (int j = 0; j < 8; ++j) acc[i][j] += av[i] * bv[j];
        }
        __syncthreads();
    }
#pragma unroll
    for (int i = 0; i < 8; ++i) {
        int m = m0 + tr * 8 + i;
        if (m < N_NODES) {
            float4 o0 = {acc[i][0], acc[i][1], acc[i][2], acc[i][3]};
            float4 o1 = {acc[i][4], acc[i][5], acc[i][6], acc[i][7]};
            *(float4*)&y[(size_t)m * N + tc * 8] = o0;
            *(float4*)&y[(size_t)m * N + tc * 8 + 4] = o1;
        }
    }
}

extern "C" void kernel_launch(void* const* d_in, const int* in_sizes, int n_in,
                              void* d_out, int out_size, void* d_ws, size_t ws_size,
                              hipStream_t stream) {
    const float* h_in = (const float*)d_in[0];
    const void* edges = d_in[1];
    const float* W[5] = {(const float*)d_in[2], (const float*)d_in[4], (const float*)d_in[6],
                         (const float*)d_in[8], (const float*)d_in[10]};
    const float* B[5] = {(const float*)d_in[3], (const float*)d_in[5], (const float*)d_in[7],
                         (const float*)d_in[9], (const float*)d_in[11]};

    size_t off = 0;
    auto alloc = [&](size_t bytes) {
        void* p = (char*)d_ws + off;
        off = (off + bytes + 255) & ~(size_t)255;
        return p;
    };
    int* esorted = (int*)alloc((size_t)N_EDGES * 4);            // 12.8 MB
    int* row_ptr = (int*)alloc((size_t)(N_NODES + 1) * 4);
    int* hist2 = (int*)alloc((size_t)NCHUNKS * NB * 4);         // 613 KB
    int* base2 = (int*)alloc((size_t)NCHUNKS * NB * 4);         // 613 KB
    int* bcount = (int*)alloc((size_t)NB * 4);
    int* boff = (int*)alloc((size_t)(NB + 1) * 4);
    int* flag = (int*)alloc(256);
    float* C = (float*)alloc((size_t)N_NODES * 128 * 4);        // 51.2 MB (gemm out p)
    float* D = (float*)alloc((size_t)N_NODES * 128 * 4);        // 51.2 MB (layer out h)
    unsigned int* tmp = (unsigned int*)D;  // alias: dead after bucket_finalize,
                                           // D first written by agg128 (later)

    // ---- build CSR (deterministic bucketed counting sort by dst) ----
    detect_fmt<<<1, 64, 0, stream>>>((const unsigned int*)edges, flag, row_ptr);
    hipMemsetAsync(bcount, 0, (size_t)NB * 4, stream);
    part_hist<<<NCHUNKS, 256, 0, stream>>>(edges, flag, hist2, bcount);
    scan_kernel<<<1, 1024, 0, stream>>>(bcount, boff, NB);
    chunk_scan<<<NB, 256, 0, stream>>>(hist2, boff, base2);
    part_scatter<<<NCHUNKS, 256, 0, stream>>>(edges, flag, base2, tmp);
    bucket_finalize<<<NB, 256, 0, stream>>>(tmp, boff, row_ptr, esorted);

    // ---- 5 GIN layers: p = h @ W; h' = p + agg(p) + b ----
    const int AGG_BLOCKS = 2048;

    mlp_gemm<128, 128><<<(N_NODES + 127) / 128, 256, 0, stream>>>(h_in, W[0], C);
    agg128<<<AGG_BLOCKS, 256, 0, stream>>>(C, row_ptr, esorted, B[0], D);
    for (int l = 1; l <= 3; ++l) {
        mlp_gemm<128, 128><<<(N_NODES + 127) / 128, 256, 0, stream>>>(D, W[l], C);
        agg128<<<AGG_BLOCKS, 256, 0, stream>>>(C, row_ptr, esorted, B[l], D);
    }
    mlp_gemm<64, 256><<<(N_NODES + 255) / 256, 256, 0, stream>>>(D, W[4], C);
    agg64<<<AGG_BLOCKS, 256, 0, stream>>>(C, row_ptr, esorted, B[4], (float*)d_out);
}

// Round 4
// 878.793 us; speedup vs baseline: 3.3490x; 1.5626x over previous
//
#include <hip/hip_runtime.h>

#define N_NODES 100000
#define N_EDGES 3200000
#define NB 782          // dst buckets of 128 nodes: ceil(100000/128)
#define BCAP 5120       // max edges per bucket (avg 4096, 16 sigma guard)
#define CHUNK_EDGES 16384
#define NCHUNKS ((N_EDGES + CHUNK_EDGES - 1) / CHUNK_EDGES)  // 196

typedef unsigned int uint;

// ---------- CSR build: deterministic two-pass bucket partition ----------

__global__ void detect_fmt(const uint* __restrict__ e, int* __restrict__ flag,
                           int* __restrict__ row_ptr) {
    if (threadIdx.x == 0) {
        *flag = (e[1] == 0u && e[3] == 0u && e[5] == 0u && e[7] == 0u) ? 1 : 0;
        row_ptr[N_NODES] = N_EDGES;
    }
}

__device__ __forceinline__ int load_idx(const void* edges, int fmt, long long i) {
    return fmt ? (int)((const long long*)edges)[i] : ((const int*)edges)[i];
}

__global__ __launch_bounds__(256) void part_hist(const void* __restrict__ edges,
                                                 const int* __restrict__ flag,
                                                 int* __restrict__ hist2,
                                                 int* __restrict__ bcount) {
    __shared__ int cnt[NB];
    for (int i = threadIdx.x; i < NB; i += 256) cnt[i] = 0;
    __syncthreads();
    int fmt = *flag;
    int c = blockIdx.x;
    int beg = c * CHUNK_EDGES, end = min(beg + CHUNK_EDGES, N_EDGES);
    for (int i = beg + threadIdx.x; i < end; i += 256) {
        int dst = load_idx(edges, fmt, (long long)N_EDGES + i);
        atomicAdd(&cnt[dst >> 7], 1);
    }
    __syncthreads();
    for (int i = threadIdx.x; i < NB; i += 256) {
        hist2[c * NB + i] = cnt[i];
        if (cnt[i]) atomicAdd(&bcount[i], cnt[i]);
    }
}

__global__ void scan_kernel(const int* __restrict__ count, int* __restrict__ off_out, int n) {
    __shared__ int sums[1024];
    int t = threadIdx.x;
    int chunk = (n + 1023) >> 10;
    int beg = t * chunk;
    int end = min(beg + chunk, n);
    int s = 0;
    for (int i = beg; i < end; ++i) s += count[i];
    sums[t] = s;
    __syncthreads();
    int val = s;
    for (int off = 1; off < 1024; off <<= 1) {
        int other = (t >= off) ? sums[t - off] : 0;
        __syncthreads();
        val += other;
        sums[t] = val;
        __syncthreads();
    }
    int run = val - s;
    for (int i = beg; i < end; ++i) {
        off_out[i] = run;
        run += count[i];
    }
    if (end >= n) off_out[n] = run;
}

__global__ __launch_bounds__(256) void chunk_scan(const int* __restrict__ hist2,
                                                  const int* __restrict__ boff,
                                                  int* __restrict__ base2) {
    __shared__ int s[256];
    int b = blockIdx.x;
    int t = threadIdx.x;
    int v = (t < NCHUNKS) ? hist2[t * NB + b] : 0;
    s[t] = v;
    __syncthreads();
    int val = v;
    for (int off = 1; off < 256; off <<= 1) {
        int o = (t >= off) ? s[t - off] : 0;
        __syncthreads();
        val += o;
        s[t] = val;
        __syncthreads();
    }
    if (t < NCHUNKS) base2[t * NB + b] = boff[b] + val - v;
}

__global__ __launch_bounds__(256) void part_scatter(const void* __restrict__ edges,
                                                    const int* __restrict__ flag,
                                                    const int* __restrict__ base2,
                                                    uint* __restrict__ tmp) {
    __shared__ int cur[NB];
    int c = blockIdx.x;
    for (int i = threadIdx.x; i < NB; i += 256) cur[i] = base2[c * NB + i];
    __syncthreads();
    int fmt = *flag;
    int beg = c * CHUNK_EDGES, end = min(beg + CHUNK_EDGES, N_EDGES);
    for (int i = beg + threadIdx.x; i < end; i += 256) {
        int src = load_idx(edges, fmt, i);
        int dst = load_idx(edges, fmt, (long long)N_EDGES + i);
        int b = dst >> 7;
        int pos = atomicAdd(&cur[b], 1);
        tmp[pos] = ((uint)(dst & 127) << 17) | (uint)src;  // src < 2^17
    }
}

__global__ __launch_bounds__(256) void bucket_finalize(const uint* __restrict__ tmp,
                                                       const int* __restrict__ boff,
                                                       int* __restrict__ row_ptr,
                                                       int* __restrict__ esorted) {
    __shared__ uint s1[BCAP];
    __shared__ int s2[BCAP];
    __shared__ int cnt[128], pref[128], cur[128];
    int b = blockIdx.x;
    int beg = boff[b];
    int n = boff[b + 1] - beg;
    if (n > BCAP) n = BCAP;
    int t = threadIdx.x;
    if (t < 128) cnt[t] = 0;
    __syncthreads();
    for (int e = t; e < n; e += 256) {
        uint k = tmp[beg + e];
        s1[e] = k;
        atomicAdd(&cnt[k >> 17], 1);
    }
    __syncthreads();
    if (t < 128) pref[t] = cnt[t];
    __syncthreads();
    for (int off = 1; off < 128; off <<= 1) {
        int v = (t < 128 && t >= off) ? pref[t - off] : 0;
        __syncthreads();
        if (t < 128) pref[t] += v;
        __syncthreads();
    }
    if (t < 128) {
        int ex = pref[t] - cnt[t];
        cur[t] = ex;
        int node = b * 128 + t;
        if (node < N_NODES) row_ptr[node] = beg + ex;
    }
    __syncthreads();
    for (int e = t; e < n; e += 256) {
        uint k = s1[e];
        int p = atomicAdd(&cur[k >> 17], 1);
        s2[p] = (int)(k & 0x1FFFF);
    }
    __syncthreads();
    for (int e = t; e < n; e += 256) esorted[beg + e] = s2[e];
}

// ---------- per-layer kernels ----------
// Layer via linearity: h' = p + agg(p) + bias, where p = h @ W.
// p is stored bf16 (packed pairs in uint) to halve gather traffic; h' stays fp32.

__device__ __forceinline__ uint bf16pack(float a, float b) {
    uint ua = __float_as_uint(a);
    ua = (ua + 0x7FFFu + ((ua >> 16) & 1u)) >> 16;  // RNE
    uint ub = __float_as_uint(b);
    ub = (ub + 0x7FFFu + ((ub >> 16) & 1u)) >> 16;
    return ua | (ub << 16);
}
__device__ __forceinline__ float bf_lo(uint u) { return __uint_as_float(u << 16); }
__device__ __forceinline__ float bf_hi(uint u) { return __uint_as_float(u & 0xFFFF0000u); }

// 128-dim bf16 rows (64 uints, 256B): lane l owns dims (2l, 2l+1) = one uint.
__global__ __launch_bounds__(256) void agg128(const uint* __restrict__ p,
                                              const int* __restrict__ row_ptr,
                                              const int* __restrict__ esrc,
                                              const float* __restrict__ bias,
                                              float* __restrict__ out) {
    int lane = threadIdx.x & 63;
    int wid = (blockIdx.x * blockDim.x + threadIdx.x) >> 6;
    int nw = (gridDim.x * blockDim.x) >> 6;
    float2 bv = ((const float2*)bias)[lane];
    for (int v = wid; v < N_NODES; v += nw) {
        uint self = p[(size_t)v * 64 + lane];
        float ax = bf_lo(self) + bv.x;
        float ay = bf_hi(self) + bv.y;
        int beg = row_ptr[v], end = row_ptr[v + 1];
        int i = beg;
        for (; i + 8 <= end; i += 8) {
            uint hv[8];
#pragma unroll
            for (int j = 0; j < 8; ++j) hv[j] = p[(size_t)esrc[i + j] * 64 + lane];
#pragma unroll
            for (int j = 0; j < 8; ++j) { ax += bf_lo(hv[j]); ay += bf_hi(hv[j]); }
        }
        for (; i < end; ++i) {
            uint u = p[(size_t)esrc[i] * 64 + lane];
            ax += bf_lo(u);
            ay += bf_hi(u);
        }
        float2 o = {ax, ay};
        ((float2*)&out[(size_t)v * 128])[lane] = o;
    }
}

// 64-dim bf16 rows (128B): lane l owns dim l (ushort load). Output fp32.
__global__ __launch_bounds__(256) void agg64(const unsigned short* __restrict__ p,
                                             const int* __restrict__ row_ptr,
                                             const int* __restrict__ esrc,
                                             const float* __restrict__ bias,
                                             float* __restrict__ out) {
    int lane = threadIdx.x & 63;
    int wid = (blockIdx.x * blockDim.x + threadIdx.x) >> 6;
    int nw = (gridDim.x * blockDim.x) >> 6;
    float bv = bias[lane];
    for (int v = wid; v < N_NODES; v += nw) {
        float a = __uint_as_float(((uint)p[(size_t)v * 64 + lane]) << 16) + bv;
        int beg = row_ptr[v], end = row_ptr[v + 1];
        int i = beg;
        for (; i + 8 <= end; i += 8) {
            uint hv[8];
#pragma unroll
            for (int j = 0; j < 8; ++j) hv[j] = p[(size_t)esrc[i + j] * 64 + lane];
#pragma unroll
            for (int j = 0; j < 8; ++j) a += __uint_as_float(hv[j] << 16);
        }
        for (; i < end; ++i) a += __uint_as_float(((uint)p[(size_t)esrc[i] * 64 + lane]) << 16);
        out[(size_t)v * 64 + lane] = a;
    }
}

// y[M x N](bf16 packed) = x[M x 128] @ W[128 x N]. x fp32 (layer 0) or bf16 packed.
// 256 threads, block tile MT x N, thread tile 8x8, K staged in LDS by 16, fp32 math.
template <int N, int MT, bool A_BF16>
__global__ __launch_bounds__(256) void mlp_gemm(const void* __restrict__ xv,
                                                const float* __restrict__ W,
                                                uint* __restrict__ y) {
    __shared__ float As[16][MT];  // k-major
    __shared__ float Bs[16][N];
    constexpr int TCN = N / 8;
    int tid = threadIdx.x;
    int tc = tid % TCN;
    int tr = tid / TCN;
    int m0 = blockIdx.x * MT;
    float acc[8][8];
#pragma unroll
    for (int i = 0; i < 8; ++i)
#pragma unroll
        for (int j = 0; j < 8; ++j) acc[i][j] = 0.0f;

    for (int k0 = 0; k0 < 128; k0 += 16) {
        if constexpr (A_BF16) {
            // bf16 rows: 16-k slice = 32B = two uint4 halves; 2 lanes per row.
            const uint4* xp = (const uint4*)xv;
#pragma unroll
            for (int i = 0; i < MT / 128; ++i) {
                int idx = tid + i * 256;
                int r = idx >> 1;
                int half = idx & 1;
                int m = m0 + r;
                if (m >= N_NODES) m = N_NODES - 1;
                uint4 u = xp[(size_t)m * 16 + k0 / 8 + half];
                int kb = half * 8;
                As[kb + 0][r] = bf_lo(u.x);
                As[kb + 1][r] = bf_hi(u.x);
                As[kb + 2][r] = bf_lo(u.y);
                As[kb + 3][r] = bf_hi(u.y);
                As[kb + 4][r] = bf_lo(u.z);
                As[kb + 5][r] = bf_hi(u.z);
                As[kb + 6][r] = bf_lo(u.w);
                As[kb + 7][r] = bf_hi(u.w);
            }
        } else {
            const float* x = (const float*)xv;
#pragma unroll
            for (int i = 0; i < MT / 64; ++i) {
                int idx = tid + i * 256;
                int c4 = idx & 3;
                int r = idx >> 2;
                int m = m0 + r;
                if (m >= N_NODES) m = N_NODES - 1;
                float4 v = *(const float4*)&x[(size_t)m * 128 + k0 + c4 * 4];
                As[c4 * 4 + 0][r] = v.x;
                As[c4 * 4 + 1][r] = v.y;
                As[c4 * 4 + 2][r] = v.z;
                As[c4 * 4 + 3][r] = v.w;
            }
        }
#pragma unroll
        for (int i = 0; i < N / 64; ++i) {
            int idx = tid + i * 256;
            int c4 = idx % (N / 4);
            int kr = idx / (N / 4);
            *(float4*)&Bs[kr][c4 * 4] = *(const float4*)&W[(size_t)(k0 + kr) * N + c4 * 4];
        }
        __syncthreads();
#pragma unroll
        for (int k = 0; k < 16; ++k) {
            float4 a0 = *(const float4*)&As[k][tr * 8];
            float4 a1 = *(const float4*)&As[k][tr * 8 + 4];
            float4 b0 = *(const float4*)&Bs[k][tc * 8];
            float4 b1 = *(const float4*)&Bs[k][tc * 8 + 4];
            float av[8] = {a0.x, a0.y, a0.z, a0.w, a1.x, a1.y, a1.z, a1.w};
            float bv[8] = {b0.x, b0.y, b0.z, b0.w, b1.x, b1.y, b1.z, b1.w};
#pragma unroll
            for (int i = 0; i < 8; ++i)
#pragma unroll
                for (int j = 0; j < 8; ++j) acc[i][j] += av[i] * bv[j];
        }
        __syncthreads();
    }
#pragma unroll
    for (int i = 0; i < 8; ++i) {
        int m = m0 + tr * 8 + i;
        if (m < N_NODES) {
            uint4 o;
            o.x = bf16pack(acc[i][0], acc[i][1]);
            o.y = bf16pack(acc[i][2], acc[i][3]);
            o.z = bf16pack(acc[i][4], acc[i][5]);
            o.w = bf16pack(acc[i][6], acc[i][7]);
            *(uint4*)&y[(size_t)m * (N / 2) + tc * 4] = o;
        }
    }
}

extern "C" void kernel_launch(void* const* d_in, const int* in_sizes, int n_in,
                              void* d_out, int out_size, void* d_ws, size_t ws_size,
                              hipStream_t stream) {
    const float* h_in = (const float*)d_in[0];
    const void* edges = d_in[1];
    const float* W[5] = {(const float*)d_in[2], (const float*)d_in[4], (const float*)d_in[6],
                         (const float*)d_in[8], (const float*)d_in[10]};
    const float* B[5] = {(const float*)d_in[3], (const float*)d_in[5], (const float*)d_in[7],
                         (const float*)d_in[9], (const float*)d_in[11]};

    size_t off = 0;
    auto alloc = [&](size_t bytes) {
        void* p = (char*)d_ws + off;
        off = (off + bytes + 255) & ~(size_t)255;
        return p;
    };
    int* esorted = (int*)alloc((size_t)N_EDGES * 4);            // 12.8 MB
    int* row_ptr = (int*)alloc((size_t)(N_NODES + 1) * 4);
    int* hist2 = (int*)alloc((size_t)NCHUNKS * NB * 4);
    int* base2 = (int*)alloc((size_t)NCHUNKS * NB * 4);
    int* bcount = (int*)alloc((size_t)NB * 4);
    int* boff = (int*)alloc((size_t)(NB + 1) * 4);
    int* flag = (int*)alloc(256);
    uint* C = (uint*)alloc((size_t)N_NODES * 64 * 4);           // 25.6 MB (p, bf16-packed)
    float* D = (float*)alloc((size_t)N_NODES * 128 * 4);        // 51.2 MB (h', fp32)
    uint* tmp = (uint*)D;  // alias: dead after bucket_finalize; D first written by agg128

    // ---- build CSR ----
    detect_fmt<<<1, 64, 0, stream>>>((const uint*)edges, flag, row_ptr);
    hipMemsetAsync(bcount, 0, (size_t)NB * 4, stream);
    part_hist<<<NCHUNKS, 256, 0, stream>>>(edges, flag, hist2, bcount);
    scan_kernel<<<1, 1024, 0, stream>>>(bcount, boff, NB);
    chunk_scan<<<NB, 256, 0, stream>>>(hist2, boff, base2);
    part_scatter<<<NCHUNKS, 256, 0, stream>>>(edges, flag, base2, tmp);
    bucket_finalize<<<NB, 256, 0, stream>>>(tmp, boff, row_ptr, esorted);

    // ---- 5 GIN layers: p = h @ W (bf16); h' = p + agg(p) + b (fp32) ----
    const int AGG_BLOCKS = 2048;

    mlp_gemm<128, 128, false><<<(N_NODES + 127) / 128, 256, 0, stream>>>(h_in, W[0], C);
    agg128<<<AGG_BLOCKS, 256, 0, stream>>>(C, row_ptr, esorted, B[0], D);
    for (int l = 1; l <= 3; ++l) {
        mlp_gemm<128, 128, false><<<(N_NODES + 127) / 128, 256, 0, stream>>>(D, W[l], C);
        agg128<<<AGG_BLOCKS, 256, 0, stream>>>(C, row_ptr, esorted, B[l], D);
    }
    mlp_gemm<64, 256, false><<<(N_NODES + 255) / 256, 256, 0, stream>>>(D, W[4], C);
    agg64<<<AGG_BLOCKS, 256, 0, stream>>>((const unsigned short*)C, row_ptr, esorted, B[4],
                                          (float*)d_out);
}

// Round 5
// 876.576 us; speedup vs baseline: 3.3575x; 1.0025x over previous
//
#include <hip/hip_runtime.h>

#define N_NODES 100000
#define N_EDGES 3200000
#define NB 782          // dst buckets of 128 nodes: ceil(100000/128)
#define BCAP 5120       // max edges per bucket (avg 4096, 16 sigma guard)
#define CHUNK_EDGES 16384
#define NCHUNKS ((N_EDGES + CHUNK_EDGES - 1) / CHUNK_EDGES)  // 196

typedef unsigned int uint;
typedef uint u4v __attribute__((ext_vector_type(4)));
typedef float f4v __attribute__((ext_vector_type(4)));

// ---------- CSR build: deterministic two-pass bucket partition ----------

__global__ void detect_fmt(const uint* __restrict__ e, int* __restrict__ flag,
                           int* __restrict__ row_ptr) {
    if (threadIdx.x == 0) {
        *flag = (e[1] == 0u && e[3] == 0u && e[5] == 0u && e[7] == 0u) ? 1 : 0;
        row_ptr[N_NODES] = N_EDGES;
    }
}

__device__ __forceinline__ int load_idx(const void* edges, int fmt, long long i) {
    return fmt ? (int)((const long long*)edges)[i] : ((const int*)edges)[i];
}

__global__ __launch_bounds__(256) void part_hist(const void* __restrict__ edges,
                                                 const int* __restrict__ flag,
                                                 int* __restrict__ hist2,
                                                 int* __restrict__ bcount) {
    __shared__ int cnt[NB];
    for (int i = threadIdx.x; i < NB; i += 256) cnt[i] = 0;
    __syncthreads();
    int fmt = *flag;
    int c = blockIdx.x;
    int beg = c * CHUNK_EDGES, end = min(beg + CHUNK_EDGES, N_EDGES);
    for (int i = beg + threadIdx.x; i < end; i += 256) {
        int dst = load_idx(edges, fmt, (long long)N_EDGES + i);
        atomicAdd(&cnt[dst >> 7], 1);
    }
    __syncthreads();
    for (int i = threadIdx.x; i < NB; i += 256) {
        hist2[c * NB + i] = cnt[i];
        if (cnt[i]) atomicAdd(&bcount[i], cnt[i]);
    }
}

__global__ void scan_kernel(const int* __restrict__ count, int* __restrict__ off_out, int n) {
    __shared__ int sums[1024];
    int t = threadIdx.x;
    int chunk = (n + 1023) >> 10;
    int beg = t * chunk;
    int end = min(beg + chunk, n);
    int s = 0;
    for (int i = beg; i < end; ++i) s += count[i];
    sums[t] = s;
    __syncthreads();
    int val = s;
    for (int off = 1; off < 1024; off <<= 1) {
        int other = (t >= off) ? sums[t - off] : 0;
        __syncthreads();
        val += other;
        sums[t] = val;
        __syncthreads();
    }
    int run = val - s;
    for (int i = beg; i < end; ++i) {
        off_out[i] = run;
        run += count[i];
    }
    if (end >= n) off_out[n] = run;
}

__global__ __launch_bounds__(256) void chunk_scan(const int* __restrict__ hist2,
                                                  const int* __restrict__ boff,
                                                  int* __restrict__ base2) {
    __shared__ int s[256];
    int b = blockIdx.x;
    int t = threadIdx.x;
    int v = (t < NCHUNKS) ? hist2[t * NB + b] : 0;
    s[t] = v;
    __syncthreads();
    int val = v;
    for (int off = 1; off < 256; off <<= 1) {
        int o = (t >= off) ? s[t - off] : 0;
        __syncthreads();
        val += o;
        s[t] = val;
        __syncthreads();
    }
    if (t < NCHUNKS) base2[t * NB + b] = boff[b] + val - v;
}

__global__ __launch_bounds__(256) void part_scatter(const void* __restrict__ edges,
                                                    const int* __restrict__ flag,
                                                    const int* __restrict__ base2,
                                                    uint* __restrict__ tmp) {
    __shared__ int cur[NB];
    int c = blockIdx.x;
    for (int i = threadIdx.x; i < NB; i += 256) cur[i] = base2[c * NB + i];
    __syncthreads();
    int fmt = *flag;
    int beg = c * CHUNK_EDGES, end = min(beg + CHUNK_EDGES, N_EDGES);
    for (int i = beg + threadIdx.x; i < end; i += 256) {
        int src = load_idx(edges, fmt, i);
        int dst = load_idx(edges, fmt, (long long)N_EDGES + i);
        int b = dst >> 7;
        int pos = atomicAdd(&cur[b], 1);
        tmp[pos] = ((uint)(dst & 127) << 17) | (uint)src;  // src < 2^17
    }
}

__global__ __launch_bounds__(256) void bucket_finalize(const uint* __restrict__ tmp,
                                                       const int* __restrict__ boff,
                                                       int* __restrict__ row_ptr,
                                                       int* __restrict__ esorted) {
    __shared__ uint s1[BCAP];
    __shared__ int s2[BCAP];
    __shared__ int cnt[128], pref[128], cur[128];
    int b = blockIdx.x;
    int beg = boff[b];
    int n = boff[b + 1] - beg;
    if (n > BCAP) n = BCAP;
    int t = threadIdx.x;
    if (t < 128) cnt[t] = 0;
    __syncthreads();
    for (int e = t; e < n; e += 256) {
        uint k = tmp[beg + e];
        s1[e] = k;
        atomicAdd(&cnt[k >> 17], 1);
    }
    __syncthreads();
    if (t < 128) pref[t] = cnt[t];
    __syncthreads();
    for (int off = 1; off < 128; off <<= 1) {
        int v = (t < 128 && t >= off) ? pref[t - off] : 0;
        __syncthreads();
        if (t < 128) pref[t] += v;
        __syncthreads();
    }
    if (t < 128) {
        int ex = pref[t] - cnt[t];
        cur[t] = ex;
        int node = b * 128 + t;
        if (node < N_NODES) row_ptr[node] = beg + ex;
    }
    __syncthreads();
    for (int e = t; e < n; e += 256) {
        uint k = s1[e];
        int p = atomicAdd(&cur[k >> 17], 1);
        s2[p] = (int)(k & 0x1FFFF);
    }
    __syncthreads();
    for (int e = t; e < n; e += 256) esorted[beg + e] = s2[e];
}

// ---------- per-layer kernels ----------
// Layer via linearity: h' = p + agg(p) + bias, where p = h @ W.
// p AND h' stored bf16-packed (uint = 2 dims). All single-use streams use
// non-temporal access so L2/L3 retain p (the randomly gathered array).

__device__ __forceinline__ uint bf16pack(float a, float b) {
    uint ua = __float_as_uint(a);
    ua = (ua + 0x7FFFu + ((ua >> 16) & 1u)) >> 16;  // RNE
    uint ub = __float_as_uint(b);
    ub = (ub + 0x7FFFu + ((ub >> 16) & 1u)) >> 16;
    return ua | (ub << 16);
}
__device__ __forceinline__ float bf_lo(uint u) { return __uint_as_float(u << 16); }
__device__ __forceinline__ float bf_hi(uint u) { return __uint_as_float(u & 0xFFFF0000u); }

// 128-dim bf16 rows (64 uints, 256B): lane l owns dims (2l, 2l+1) = one uint.
// Output h' also bf16-packed, non-temporal (single-use stream).
__global__ __launch_bounds__(256) void agg128(const uint* __restrict__ p,
                                              const int* __restrict__ row_ptr,
                                              const int* __restrict__ esrc,
                                              const float* __restrict__ bias,
                                              uint* __restrict__ out) {
    int lane = threadIdx.x & 63;
    int wid = (blockIdx.x * blockDim.x + threadIdx.x) >> 6;
    int nw = (gridDim.x * blockDim.x) >> 6;
    float2 bv = ((const float2*)bias)[lane];
    for (int v = wid; v < N_NODES; v += nw) {
        uint self = p[(size_t)v * 64 + lane];
        float ax = bf_lo(self) + bv.x;
        float ay = bf_hi(self) + bv.y;
        int beg = row_ptr[v], end = row_ptr[v + 1];
        int i = beg;
        for (; i + 8 <= end; i += 8) {
            uint hv[8];
#pragma unroll
            for (int j = 0; j < 8; ++j) hv[j] = p[(size_t)esrc[i + j] * 64 + lane];
#pragma unroll
            for (int j = 0; j < 8; ++j) { ax += bf_lo(hv[j]); ay += bf_hi(hv[j]); }
        }
        for (; i < end; ++i) {
            uint u = p[(size_t)esrc[i] * 64 + lane];
            ax += bf_lo(u);
            ay += bf_hi(u);
        }
        __builtin_nontemporal_store(bf16pack(ax, ay), &out[(size_t)v * 64 + lane]);
    }
}

// 64-dim bf16 rows (128B): lane l owns dim l. Output fp32 (d_out), non-temporal.
__global__ __launch_bounds__(256) void agg64(const unsigned short* __restrict__ p,
                                             const int* __restrict__ row_ptr,
                                             const int* __restrict__ esrc,
                                             const float* __restrict__ bias,
                                             float* __restrict__ out) {
    int lane = threadIdx.x & 63;
    int wid = (blockIdx.x * blockDim.x + threadIdx.x) >> 6;
    int nw = (gridDim.x * blockDim.x) >> 6;
    float bv = bias[lane];
    for (int v = wid; v < N_NODES; v += nw) {
        float a = __uint_as_float(((uint)p[(size_t)v * 64 + lane]) << 16) + bv;
        int beg = row_ptr[v], end = row_ptr[v + 1];
        int i = beg;
        for (; i + 8 <= end; i += 8) {
            uint hv[8];
#pragma unroll
            for (int j = 0; j < 8; ++j) hv[j] = p[(size_t)esrc[i + j] * 64 + lane];
#pragma unroll
            for (int j = 0; j < 8; ++j) a += __uint_as_float(hv[j] << 16);
        }
        for (; i < end; ++i) a += __uint_as_float(((uint)p[(size_t)esrc[i] * 64 + lane]) << 16);
        __builtin_nontemporal_store(a, &out[(size_t)v * 64 + lane]);
    }
}

// y[M x N](bf16 packed) = x[M x 128] @ W[128 x N]. x fp32 (layer 0) or bf16 packed.
// A-loads non-temporal (single-use); W cached; y (=p) cached for the gather.
template <int N, int MT, bool A_BF16>
__global__ __launch_bounds__(256) void mlp_gemm(const void* __restrict__ xv,
                                                const float* __restrict__ W,
                                                uint* __restrict__ y) {
    __shared__ float As[16][MT];  // k-major
    __shared__ float Bs[16][N];
    constexpr int TCN = N / 8;
    int tid = threadIdx.x;
    int tc = tid % TCN;
    int tr = tid / TCN;
    int m0 = blockIdx.x * MT;
    float acc[8][8];
#pragma unroll
    for (int i = 0; i < 8; ++i)
#pragma unroll
        for (int j = 0; j < 8; ++j) acc[i][j] = 0.0f;

    for (int k0 = 0; k0 < 128; k0 += 16) {
        if constexpr (A_BF16) {
            const u4v* xp = (const u4v*)xv;
#pragma unroll
            for (int i = 0; i < MT / 128; ++i) {
                int idx = tid + i * 256;
                int r = idx >> 1;
                int half = idx & 1;
                int m = m0 + r;
                if (m >= N_NODES) m = N_NODES - 1;
                u4v u = __builtin_nontemporal_load(&xp[(size_t)m * 16 + k0 / 8 + half]);
                int kb = half * 8;
                As[kb + 0][r] = bf_lo(u[0]);
                As[kb + 1][r] = bf_hi(u[0]);
                As[kb + 2][r] = bf_lo(u[1]);
                As[kb + 3][r] = bf_hi(u[1]);
                As[kb + 4][r] = bf_lo(u[2]);
                As[kb + 5][r] = bf_hi(u[2]);
                As[kb + 6][r] = bf_lo(u[3]);
                As[kb + 7][r] = bf_hi(u[3]);
            }
        } else {
            const f4v* x = (const f4v*)xv;
#pragma unroll
            for (int i = 0; i < MT / 64; ++i) {
                int idx = tid + i * 256;
                int c4 = idx & 3;
                int r = idx >> 2;
                int m = m0 + r;
                if (m >= N_NODES) m = N_NODES - 1;
                f4v v = __builtin_nontemporal_load(&x[(size_t)m * 32 + k0 / 4 + c4]);
                As[c4 * 4 + 0][r] = v[0];
                As[c4 * 4 + 1][r] = v[1];
                As[c4 * 4 + 2][r] = v[2];
                As[c4 * 4 + 3][r] = v[3];
            }
        }
#pragma unroll
        for (int i = 0; i < N / 64; ++i) {
            int idx = tid + i * 256;
            int c4 = idx % (N / 4);
            int kr = idx / (N / 4);
            *(float4*)&Bs[kr][c4 * 4] = *(const float4*)&W[(size_t)(k0 + kr) * N + c4 * 4];
        }
        __syncthreads();
#pragma unroll
        for (int k = 0; k < 16; ++k) {
            float4 a0 = *(const float4*)&As[k][tr * 8];
            float4 a1 = *(const float4*)&As[k][tr * 8 + 4];
            float4 b0 = *(const float4*)&Bs[k][tc * 8];
            float4 b1 = *(const float4*)&Bs[k][tc * 8 + 4];
            float av[8] = {a0.x, a0.y, a0.z, a0.w, a1.x, a1.y, a1.z, a1.w};
            float bv[8] = {b0.x, b0.y, b0.z, b0.w, b1.x, b1.y, b1.z, b1.w};
#pragma unroll
            for (int i = 0; i < 8; ++i)
#pragma unroll
                for (int j = 0; j < 8; ++j) acc[i][j] += av[i] * bv[j];
        }
        __syncthreads();
    }
#pragma unroll
    for (int i = 0; i < 8; ++i) {
        int m = m0 + tr * 8 + i;
        if (m < N_NODES) {
            uint4 o;
            o.x = bf16pack(acc[i][0], acc[i][1]);
            o.y = bf16pack(acc[i][2], acc[i][3]);
            o.z = bf16pack(acc[i][4], acc[i][5]);
            o.w = bf16pack(acc[i][6], acc[i][7]);
            *(uint4*)&y[(size_t)m * (N / 2) + tc * 4] = o;
        }
    }
}

extern "C" void kernel_launch(void* const* d_in, const int* in_sizes, int n_in,
                              void* d_out, int out_size, void* d_ws, size_t ws_size,
                              hipStream_t stream) {
    const float* h_in = (const float*)d_in[0];
    const void* edges = d_in[1];
    const float* W[5] = {(const float*)d_in[2], (const float*)d_in[4], (const float*)d_in[6],
                         (const float*)d_in[8], (const float*)d_in[10]};
    const float* B[5] = {(const float*)d_in[3], (const float*)d_in[5], (const float*)d_in[7],
                         (const float*)d_in[9], (const float*)d_in[11]};

    size_t off = 0;
    auto alloc = [&](size_t bytes) {
        void* p = (char*)d_ws + off;
        off = (off + bytes + 255) & ~(size_t)255;
        return p;
    };
    int* esorted = (int*)alloc((size_t)N_EDGES * 4);            // 12.8 MB
    int* row_ptr = (int*)alloc((size_t)(N_NODES + 1) * 4);
    int* hist2 = (int*)alloc((size_t)NCHUNKS * NB * 4);
    int* base2 = (int*)alloc((size_t)NCHUNKS * NB * 4);
    int* bcount = (int*)alloc((size_t)NB * 4);
    int* boff = (int*)alloc((size_t)(NB + 1) * 4);
    int* flag = (int*)alloc(256);
    uint* C = (uint*)alloc((size_t)N_NODES * 64 * 4);           // 25.6 MB (p, bf16-packed)
    uint* D = (uint*)alloc((size_t)N_NODES * 64 * 4);           // 25.6 MB (h', bf16-packed)
    uint* tmp = (uint*)alloc((size_t)N_EDGES * 4);              // 12.8 MB (build only)

    // ---- build CSR ----
    detect_fmt<<<1, 64, 0, stream>>>((const uint*)edges, flag, row_ptr);
    hipMemsetAsync(bcount, 0, (size_t)NB * 4, stream);
    part_hist<<<NCHUNKS, 256, 0, stream>>>(edges, flag, hist2, bcount);
    scan_kernel<<<1, 1024, 0, stream>>>(bcount, boff, NB);
    chunk_scan<<<NB, 256, 0, stream>>>(hist2, boff, base2);
    part_scatter<<<NCHUNKS, 256, 0, stream>>>(edges, flag, base2, tmp);
    bucket_finalize<<<NB, 256, 0, stream>>>(tmp, boff, row_ptr, esorted);

    // ---- 5 GIN layers: p = h @ W (bf16); h' = p + agg(p) + b (bf16) ----
    const int AGG_BLOCKS = 2048;

    mlp_gemm<128, 128, false><<<(N_NODES + 127) / 128, 256, 0, stream>>>(h_in, W[0], C);
    agg128<<<AGG_BLOCKS, 256, 0, stream>>>(C, row_ptr, esorted, B[0], D);
    for (int l = 1; l <= 3; ++l) {
        mlp_gemm<128, 128, true><<<(N_NODES + 127) / 128, 256, 0, stream>>>(D, W[l], C);
        agg128<<<AGG_BLOCKS, 256, 0, stream>>>(C, row_ptr, esorted, B[l], D);
    }
    mlp_gemm<64, 256, true><<<(N_NODES + 255) / 256, 256, 0, stream>>>(D, W[4], C);
    agg64<<<AGG_BLOCKS, 256, 0, stream>>>((const unsigned short*)C, row_ptr, esorted, B[4],
                                          (float*)d_out);
}

// Round 6
// 728.709 us; speedup vs baseline: 4.0388x; 1.2029x over previous
//
#include <hip/hip_runtime.h>

#define N_NODES 100000
#define N_EDGES 3200000
#define NB 782          // dst buckets of 128 nodes: ceil(100000/128)
#define BCAP 5120       // max edges per bucket (avg 4096, 16 sigma guard)
#define CHUNK_EDGES 16384
#define NCHUNKS ((N_EDGES + CHUNK_EDGES - 1) / CHUNK_EDGES)  // 196

typedef unsigned int uint;
typedef __attribute__((ext_vector_type(4))) uint u4v;
typedef __attribute__((ext_vector_type(8))) short s8v;   // 8 bf16 (4 VGPRs)
typedef __attribute__((ext_vector_type(4))) float f32x4; // mfma acc

// ---------- CSR build: deterministic two-pass bucket partition ----------

__global__ void detect_fmt(const uint* __restrict__ e, int* __restrict__ flag,
                           int* __restrict__ row_ptr) {
    if (threadIdx.x == 0) {
        *flag = (e[1] == 0u && e[3] == 0u && e[5] == 0u && e[7] == 0u) ? 1 : 0;
        row_ptr[N_NODES] = N_EDGES;
    }
}

__device__ __forceinline__ int load_idx(const void* edges, int fmt, long long i) {
    return fmt ? (int)((const long long*)edges)[i] : ((const int*)edges)[i];
}

__global__ __launch_bounds__(256) void part_hist(const void* __restrict__ edges,
                                                 const int* __restrict__ flag,
                                                 int* __restrict__ hist2,
                                                 int* __restrict__ bcount) {
    __shared__ int cnt[NB];
    for (int i = threadIdx.x; i < NB; i += 256) cnt[i] = 0;
    __syncthreads();
    int fmt = *flag;
    int c = blockIdx.x;
    int beg = c * CHUNK_EDGES, end = min(beg + CHUNK_EDGES, N_EDGES);
    for (int i = beg + threadIdx.x; i < end; i += 256) {
        int dst = load_idx(edges, fmt, (long long)N_EDGES + i);
        atomicAdd(&cnt[dst >> 7], 1);
    }
    __syncthreads();
    for (int i = threadIdx.x; i < NB; i += 256) {
        hist2[c * NB + i] = cnt[i];
        if (cnt[i]) atomicAdd(&bcount[i], cnt[i]);
    }
}

__global__ void scan_kernel(const int* __restrict__ count, int* __restrict__ off_out, int n) {
    __shared__ int sums[1024];
    int t = threadIdx.x;
    int chunk = (n + 1023) >> 10;
    int beg = t * chunk;
    int end = min(beg + chunk, n);
    int s = 0;
    for (int i = beg; i < end; ++i) s += count[i];
    sums[t] = s;
    __syncthreads();
    int val = s;
    for (int off = 1; off < 1024; off <<= 1) {
        int other = (t >= off) ? sums[t - off] : 0;
        __syncthreads();
        val += other;
        sums[t] = val;
        __syncthreads();
    }
    int run = val - s;
    for (int i = beg; i < end; ++i) {
        off_out[i] = run;
        run += count[i];
    }
    if (end >= n) off_out[n] = run;
}

__global__ __launch_bounds__(256) void chunk_scan(const int* __restrict__ hist2,
                                                  const int* __restrict__ boff,
                                                  int* __restrict__ base2) {
    __shared__ int s[256];
    int b = blockIdx.x;
    int t = threadIdx.x;
    int v = (t < NCHUNKS) ? hist2[t * NB + b] : 0;
    s[t] = v;
    __syncthreads();
    int val = v;
    for (int off = 1; off < 256; off <<= 1) {
        int o = (t >= off) ? s[t - off] : 0;
        __syncthreads();
        val += o;
        s[t] = val;
        __syncthreads();
    }
    if (t < NCHUNKS) base2[t * NB + b] = boff[b] + val - v;
}

__global__ __launch_bounds__(256) void part_scatter(const void* __restrict__ edges,
                                                    const int* __restrict__ flag,
                                                    const int* __restrict__ base2,
                                                    uint* __restrict__ tmp) {
    __shared__ int cur[NB];
    int c = blockIdx.x;
    for (int i = threadIdx.x; i < NB; i += 256) cur[i] = base2[c * NB + i];
    __syncthreads();
    int fmt = *flag;
    int beg = c * CHUNK_EDGES, end = min(beg + CHUNK_EDGES, N_EDGES);
    for (int i = beg + threadIdx.x; i < end; i += 256) {
        int src = load_idx(edges, fmt, i);
        int dst = load_idx(edges, fmt, (long long)N_EDGES + i);
        int b = dst >> 7;
        int pos = atomicAdd(&cur[b], 1);
        tmp[pos] = ((uint)(dst & 127) << 17) | (uint)src;  // src < 2^17
    }
}

__global__ __launch_bounds__(256) void bucket_finalize(const uint* __restrict__ tmp,
                                                       const int* __restrict__ boff,
                                                       int* __restrict__ row_ptr,
                                                       int* __restrict__ esorted) {
    __shared__ uint s1[BCAP];
    __shared__ int s2[BCAP];
    __shared__ int cnt[128], pref[128], cur[128];
    int b = blockIdx.x;
    int beg = boff[b];
    int n = boff[b + 1] - beg;
    if (n > BCAP) n = BCAP;
    int t = threadIdx.x;
    if (t < 128) cnt[t] = 0;
    __syncthreads();
    for (int e = t; e < n; e += 256) {
        uint k = tmp[beg + e];
        s1[e] = k;
        atomicAdd(&cnt[k >> 17], 1);
    }
    __syncthreads();
    if (t < 128) pref[t] = cnt[t];
    __syncthreads();
    for (int off = 1; off < 128; off <<= 1) {
        int v = (t < 128 && t >= off) ? pref[t - off] : 0;
        __syncthreads();
        if (t < 128) pref[t] += v;
        __syncthreads();
    }
    if (t < 128) {
        int ex = pref[t] - cnt[t];
        cur[t] = ex;
        int node = b * 128 + t;
        if (node < N_NODES) row_ptr[node] = beg + ex;
    }
    __syncthreads();
    for (int e = t; e < n; e += 256) {
        uint k = s1[e];
        int p = atomicAdd(&cur[k >> 17], 1);
        s2[p] = (int)(k & 0x1FFFF);
    }
    __syncthreads();
    for (int e = t; e < n; e += 256) esorted[beg + e] = s2[e];
}

// ---------- bf16 helpers ----------

__device__ __forceinline__ uint bf16pack(float a, float b) {
    uint ua = __float_as_uint(a);
    ua = (ua + 0x7FFFu + ((ua >> 16) & 1u)) >> 16;  // RNE
    uint ub = __float_as_uint(b);
    ub = (ub + 0x7FFFu + ((ub >> 16) & 1u)) >> 16;
    return ua | (ub << 16);
}
__device__ __forceinline__ float bf_lo(uint u) { return __uint_as_float(u << 16); }
__device__ __forceinline__ float bf_hi(uint u) { return __uint_as_float(u & 0xFFFF0000u); }

// ---------- aggregation ----------
// h' = p + agg(p) + bias; p bf16-packed. Unroll 16 for miss-path parallelism.

__global__ __launch_bounds__(256) void agg128(const uint* __restrict__ p,
                                              const int* __restrict__ row_ptr,
                                              const int* __restrict__ esrc,
                                              const float* __restrict__ bias,
                                              uint* __restrict__ out) {
    int lane = threadIdx.x & 63;
    int wid = (blockIdx.x * blockDim.x + threadIdx.x) >> 6;
    int nw = (gridDim.x * blockDim.x) >> 6;
    float2 bv = ((const float2*)bias)[lane];
    for (int v = wid; v < N_NODES; v += nw) {
        uint self = p[(size_t)v * 64 + lane];
        float ax = bf_lo(self) + bv.x;
        float ay = bf_hi(self) + bv.y;
        int beg = row_ptr[v], end = row_ptr[v + 1];
        int i = beg;
        for (; i + 16 <= end; i += 16) {
            uint hv[16];
#pragma unroll
            for (int j = 0; j < 16; ++j) hv[j] = p[(size_t)esrc[i + j] * 64 + lane];
#pragma unroll
            for (int j = 0; j < 16; ++j) { ax += bf_lo(hv[j]); ay += bf_hi(hv[j]); }
        }
        for (; i + 4 <= end; i += 4) {
            uint hv[4];
#pragma unroll
            for (int j = 0; j < 4; ++j) hv[j] = p[(size_t)esrc[i + j] * 64 + lane];
#pragma unroll
            for (int j = 0; j < 4; ++j) { ax += bf_lo(hv[j]); ay += bf_hi(hv[j]); }
        }
        for (; i < end; ++i) {
            uint u = p[(size_t)esrc[i] * 64 + lane];
            ax += bf_lo(u);
            ay += bf_hi(u);
        }
        __builtin_nontemporal_store(bf16pack(ax, ay), &out[(size_t)v * 64 + lane]);
    }
}

__global__ __launch_bounds__(256) void agg64(const unsigned short* __restrict__ p,
                                             const int* __restrict__ row_ptr,
                                             const int* __restrict__ esrc,
                                             const float* __restrict__ bias,
                                             float* __restrict__ out) {
    int lane = threadIdx.x & 63;
    int wid = (blockIdx.x * blockDim.x + threadIdx.x) >> 6;
    int nw = (gridDim.x * blockDim.x) >> 6;
    float bv = bias[lane];
    for (int v = wid; v < N_NODES; v += nw) {
        float a = __uint_as_float(((uint)p[(size_t)v * 64 + lane]) << 16) + bv;
        int beg = row_ptr[v], end = row_ptr[v + 1];
        int i = beg;
        for (; i + 16 <= end; i += 16) {
            uint hv[16];
#pragma unroll
            for (int j = 0; j < 16; ++j) hv[j] = p[(size_t)esrc[i + j] * 64 + lane];
#pragma unroll
            for (int j = 0; j < 16; ++j) a += __uint_as_float(hv[j] << 16);
        }
        for (; i < end; ++i) a += __uint_as_float(((uint)p[(size_t)esrc[i] * 64 + lane]) << 16);
        __builtin_nontemporal_store(a, &out[(size_t)v * 64 + lane]);
    }
}

// ---------- MFMA GEMM ----------
// Per layer: prep_w transposes W (fp32 [128][NOUT]) -> Wt bf16, [n][c16] uint4
// units (c16 = 8-k chunk), XOR-swizzled (c16 ^= n&7) to kill the 16-way LDS
// bank conflict of the 256B-stride fragment reads (G4).

template <int NOUT>
__global__ __launch_bounds__(256) void prep_w(const float* __restrict__ W,
                                              u4v* __restrict__ Wt) {
    int idx = blockIdx.x * 256 + threadIdx.x;  // n*16 + c16
    if (idx >= NOUT * 16) return;
    int n = idx >> 4, c16 = idx & 15;
    u4v o;
#pragma unroll
    for (int q = 0; q < 4; ++q)
        o[q] = bf16pack(W[(size_t)(c16 * 8 + 2 * q) * NOUT + n],
                        W[(size_t)(c16 * 8 + 2 * q + 1) * NOUT + n]);
    Wt[n * 16 + (c16 ^ (n & 7))] = o;
}

// y[M x NOUT] (bf16-packed) = x[M x 128] @ W. Block: 128 rows, 4 waves.
// Wave w: n-strip of NOUT/4; frags: 8 (m) x NF (n) of mfma_f32_16x16x32_bf16.
// A-frag: lane holds A[row = lane&15][k = (lane>>4)*8 + j]; B-frag:
// B[k][col = lane&15]; D: row = (lane>>4)*4 + r, col = lane&15.
template <int NOUT, bool A_BF16>
__global__ __launch_bounds__(256) void mfma_gemm(const void* __restrict__ xv,
                                                 const u4v* __restrict__ Wt,
                                                 uint* __restrict__ y) {
    constexpr int STAGE = 32768 + NOUT * 256;        // A (32K) + B
    constexpr int EPIL = 128 * NOUT * 4;             // fp32 C tile
    constexpr int SMEM = STAGE > EPIL ? STAGE : EPIL;
    __shared__ char raw[SMEM];
    u4v* Asm = (u4v*)raw;                  // [128][16] swizzled
    u4v* Bsm = (u4v*)(raw + 32768);        // [NOUT][16] swizzled
    float* Cst = (float*)raw;              // [128][NOUT] epilogue overlay
    int tid = threadIdx.x;
    int m0 = blockIdx.x * 128;

    if constexpr (A_BF16) {
        const u4v* xp = (const u4v*)xv;
#pragma unroll
        for (int i = 0; i < 8; ++i) {
            int idx = tid + i * 256;
            int r = idx >> 4, c16 = idx & 15;
            int m = m0 + r;
            if (m >= N_NODES) m = N_NODES - 1;
            Asm[r * 16 + (c16 ^ (r & 7))] = xp[(size_t)m * 16 + c16];
        }
    } else {
        const float* x = (const float*)xv;
#pragma unroll
        for (int i = 0; i < 8; ++i) {
            int idx = tid + i * 256;
            int r = idx >> 4, c16 = idx & 15;
            int m = m0 + r;
            if (m >= N_NODES) m = N_NODES - 1;
            const float* src = &x[(size_t)m * 128 + c16 * 8];
            float4 v0 = *(const float4*)src;
            float4 v1 = *(const float4*)(src + 4);
            u4v o = {bf16pack(v0.x, v0.y), bf16pack(v0.z, v0.w),
                     bf16pack(v1.x, v1.y), bf16pack(v1.z, v1.w)};
            Asm[r * 16 + (c16 ^ (r & 7))] = o;
        }
    }
#pragma unroll
    for (int i = 0; i < NOUT * 16 / 256; ++i) Bsm[tid + i * 256] = Wt[tid + i * 256];
    __syncthreads();

    constexpr int NF = NOUT / 64;  // n-frags per wave (2 for 128, 1 for 64)
    int lane = tid & 63;
    int w = tid >> 6;
    int n0w = w * (NOUT / 4);
    int lhi = lane >> 4, llo = lane & 15;
    f32x4 acc[8][NF];
#pragma unroll
    for (int i = 0; i < 8; ++i)
#pragma unroll
        for (int j = 0; j < NF; ++j) acc[i][j] = (f32x4){0.f, 0.f, 0.f, 0.f};

#pragma unroll
    for (int ks = 0; ks < 4; ++ks) {
        int cb = ks * 4 + lhi;
        s8v b[NF];
#pragma unroll
        for (int j = 0; j < NF; ++j) {
            int col = n0w + j * 16 + llo;
            u4v t = Bsm[col * 16 + (cb ^ (col & 7))];
            b[j] = *(s8v*)&t;
        }
#pragma unroll
        for (int i = 0; i < 8; ++i) {
            int row = i * 16 + llo;
            u4v t = Asm[row * 16 + (cb ^ (row & 7))];
            s8v a = *(s8v*)&t;
#pragma unroll
            for (int j = 0; j < NF; ++j)
                acc[i][j] = __builtin_amdgcn_mfma_f32_16x16x32_bf16(a, b[j], acc[i][j], 0, 0, 0);
        }
    }
    __syncthreads();
#pragma unroll
    for (int i = 0; i < 8; ++i)
#pragma unroll
        for (int j = 0; j < NF; ++j)
#pragma unroll
            for (int r = 0; r < 4; ++r)
                Cst[(i * 16 + lhi * 4 + r) * NOUT + n0w + j * 16 + llo] = acc[i][j][r];
    __syncthreads();
#pragma unroll
    for (int i = 0; i < 128 * NOUT / 2 / 256; ++i) {
        int idx = tid + i * 256;
        int m = idx / (NOUT / 2), np = idx % (NOUT / 2);
        if (m0 + m < N_NODES)
            y[(size_t)(m0 + m) * (NOUT / 2) + np] =
                bf16pack(Cst[m * NOUT + 2 * np], Cst[m * NOUT + 2 * np + 1]);
    }
}

extern "C" void kernel_launch(void* const* d_in, const int* in_sizes, int n_in,
                              void* d_out, int out_size, void* d_ws, size_t ws_size,
                              hipStream_t stream) {
    const float* h_in = (const float*)d_in[0];
    const void* edges = d_in[1];
    const float* W[5] = {(const float*)d_in[2], (const float*)d_in[4], (const float*)d_in[6],
                         (const float*)d_in[8], (const float*)d_in[10]};
    const float* B[5] = {(const float*)d_in[3], (const float*)d_in[5], (const float*)d_in[7],
                         (const float*)d_in[9], (const float*)d_in[11]};

    size_t off = 0;
    auto alloc = [&](size_t bytes) {
        void* p = (char*)d_ws + off;
        off = (off + bytes + 255) & ~(size_t)255;
        return p;
    };
    int* esorted = (int*)alloc((size_t)N_EDGES * 4);       // 12.8 MB
    int* row_ptr = (int*)alloc((size_t)(N_NODES + 1) * 4);
    int* hist2 = (int*)alloc((size_t)NCHUNKS * NB * 4);
    int* base2 = (int*)alloc((size_t)NCHUNKS * NB * 4);
    int* bcount = (int*)alloc((size_t)NB * 4);
    int* boff = (int*)alloc((size_t)(NB + 1) * 4);
    int* flag = (int*)alloc(256);
    u4v* Wt[5];
    for (int l = 0; l < 5; ++l) Wt[l] = (u4v*)alloc((size_t)128 * 16 * 16);
    uint* C = (uint*)alloc((size_t)N_NODES * 64 * 4);      // 25.6 MB (p, bf16)
    uint* D = (uint*)alloc((size_t)N_NODES * 64 * 4);      // 25.6 MB (h', bf16)
    uint* tmp = (uint*)alloc((size_t)N_EDGES * 4);         // 12.8 MB (build only)

    // ---- build CSR ----
    detect_fmt<<<1, 64, 0, stream>>>((const uint*)edges, flag, row_ptr);
    hipMemsetAsync(bcount, 0, (size_t)NB * 4, stream);
    part_hist<<<NCHUNKS, 256, 0, stream>>>(edges, flag, hist2, bcount);
    scan_kernel<<<1, 1024, 0, stream>>>(bcount, boff, NB);
    chunk_scan<<<NB, 256, 0, stream>>>(hist2, boff, base2);
    part_scatter<<<NCHUNKS, 256, 0, stream>>>(edges, flag, base2, tmp);
    bucket_finalize<<<NB, 256, 0, stream>>>(tmp, boff, row_ptr, esorted);

    // ---- weight prep (bf16 transpose + swizzle) ----
    for (int l = 0; l < 4; ++l) prep_w<128><<<8, 256, 0, stream>>>(W[l], Wt[l]);
    prep_w<64><<<4, 256, 0, stream>>>(W[4], Wt[4]);

    // ---- 5 GIN layers: p = h @ W (MFMA, bf16); h' = p + agg(p) + b ----
    const int NBLK = (N_NODES + 127) / 128;  // 782

    mfma_gemm<128, false><<<NBLK, 256, 0, stream>>>(h_in, Wt[0], C);
    agg128<<<4096, 256, 0, stream>>>(C, row_ptr, esorted, B[0], D);
    for (int l = 1; l <= 3; ++l) {
        mfma_gemm<128, true><<<NBLK, 256, 0, stream>>>(D, Wt[l], C);
        agg128<<<4096, 256, 0, stream>>>(C, row_ptr, esorted, B[l], D);
    }
    mfma_gemm<64, true><<<NBLK, 256, 0, stream>>>(D, Wt[4], C);
    agg64<<<2048, 256, 0, stream>>>((const unsigned short*)C, row_ptr, esorted, B[4],
                                    (float*)d_out);
}